// Round 8
// baseline (494.220 us; speedup 1.0000x reference)
//
#include <hip/hip_runtime.h>
#include <hip/hip_bf16.h>
#include <math.h>

typedef __attribute__((ext_vector_type(8))) short short8;
typedef __attribute__((ext_vector_type(4))) float f32x4;
typedef __attribute__((ext_vector_type(2))) float f32x2;

#define LOG2E 1.4426950408889634f
#define LN2   0.6931471805599453f

__device__ __forceinline__ unsigned short f2bf(float f) {
    union { float f; unsigned u; } v; v.f = f;
    unsigned u = v.u;
    u += 0x7fffu + ((u >> 16) & 1u);   // RNE, finite
    return (unsigned short)(u >> 16);
}
__device__ __forceinline__ float bf2f(unsigned short h) {
    union { unsigned u; float f; } v; v.u = ((unsigned)h) << 16;
    return v.f;
}
__device__ __forceinline__ unsigned pk_bf16(float a, float b) {
    __hip_bfloat162 t = __float22bfloat162_rn(float2{a, b});   // v_cvt_pk_bf16_f32
    union { __hip_bfloat162 b; unsigned u; } v; v.b = t;
    return v.u;
}
// packed FP32 ops (VOP3P, CDNA2+)
__device__ __forceinline__ f32x2 pk_add2(f32x2 a, f32x2 b) {
    f32x2 d;
    asm("v_pk_add_f32 %0, %1, %2" : "=v"(d) : "v"(a), "v"(b));
    return d;
}
__device__ __forceinline__ f32x2 pk_mul2(f32x2 a, f32x2 b) {
    f32x2 d;
    asm("v_pk_mul_f32 %0, %1, %2" : "=v"(d) : "v"(a), "v"(b));
    return d;
}

// ---------------------------------------------------------------------------
// R8 STRUCTURE: 512-thread blocks, 8 waves, 128 rows = two 64-row tiles A,B.
// Wave w owns phys cols [w*32, w*32+32): 2 col-tiles ct (0..1), frag col i:
// n = w*32 + 2*i + ct. Alternating-layer pipeline, one barrier per region:
//   R0: mfmaA(0); mfmaB(0); actA(0)        | R1: mfmaA(1) || actB(0)
//   R2: mfmaB(1) || actA(1)                | R3: mfmaA(2) || actB(1)
//   R4: mfmaB(2) || actA(2)                | R5: mfma3A   || actB(2)
//   R6: mfma3B || scrA                     | R7: reduceA || scrB; R8: reduceB
// act_store(Y) has NO dep on the just-issued mfma(X) -> the wave's VALU
// (exp2-heavy activation) executes while its MFMA chains drain: intra-wave
// MFMA||VALU overlap by construction (fix for measured MfmaUtil+VALUBusy
// ~= 95%, i.e. serial phases).
// Pack (per-wave contiguous streams):
//   W0 (K=9 pad 32, hi/lo rows [wh,wl,wh]):
//     wp[((w*2+ct)*64+lane)*8+j], k=(lane>>4)*8+j, n=w*32+2*(lane&15)+ct
//   W1 @8192 / W2 @73728 (NKS=8):
//     wp[off+(((w*8+ks)*2+ct)*64+lane)*8+j], k=ks*32+(lane>>4)*8+j, n as above
//   W3 @139264 (per-wave K-slice 32, hi/lo in B-cols 0/1):
//     wp[139264+((w*64+lane)*8+j)], k=w*32+(lane>>4)*8+j
// SCALE FOLD: s_n = sqrt(log2e/(2 sigma^2)) folded into W; t_n = s_n*b_n;
// gauss = exp2(-(u+t)^2): pk_add + pk_mul + exp2(neg mod). negc[l*256+n]=t_n.
// Register budget: accA+accB = 64 AGPR + ~55 VGPR <= 128 -> 4 waves/SIMD
// (R2: crossing 128 halves residency). __launch_bounds__(512,4) pins it.
// LDS: hA+hB+A0 = 33792*2+10240 = 77824 -> 2 blocks/CU.
// ---------------------------------------------------------------------------
__global__ void pack_kernel(const float* __restrict__ W0, const float* __restrict__ W1,
                            const float* __restrict__ W2, const float* __restrict__ W3,
                            const float* __restrict__ s0, const float* __restrict__ s1,
                            const float* __restrict__ s2,
                            const float* __restrict__ b0, const float* __restrict__ b1,
                            const float* __restrict__ b2,
                            unsigned short* __restrict__ wp, float* __restrict__ negc) {
    int tid = blockIdx.x * 256 + threadIdx.x;    // 0 .. 143359
    if (tid < 8192) {                            // W0: 8w x 1ks x 2ct, scaled hi/lo
        int j = tid & 7, lane = (tid >> 3) & 63, ct = (tid >> 9) & 1, w = (tid >> 10) & 7;
        int k = ((lane >> 4) * 8) + j;           // 0..31
        int n = w * 32 + 2 * (lane & 15) + ct;
        unsigned short v = 0;
        if (k < 9) {
            int d = k / 3, m = k - d * 3;        // m: 0->wh 1->wl 2->wh
            float sv = s0[n];
            float sc = sqrtf(LOG2E / (2.0f * sv * sv));
            float wv = W0[d * 256 + n] * sc;
            unsigned short wh = f2bf(wv);
            v = (m == 1) ? f2bf(wv - bf2f(wh)) : wh;
        }
        wp[tid] = v;
    } else if (tid < 139264) {                   // W1 / W2: 8w x 8ks x 2ct, scaled
        int e = tid - 8192;
        const float* W = W1;
        const float* S = s1;
        if (e >= 65536) { W = W2; S = s2; e -= 65536; }
        int j = e & 7, lane = (e >> 3) & 63, ct = (e >> 9) & 1, ks = (e >> 10) & 7, w = (e >> 13) & 7;
        int k = ks * 32 + ((lane >> 4) * 8) + j;
        int n = w * 32 + 2 * (lane & 15) + ct;
        float sv = S[n];
        float sc = sqrtf(LOG2E / (2.0f * sv * sv));
        wp[tid] = f2bf(W[k * 256 + n] * sc);     // full-offset store (R4 lesson)
    } else if (tid < 143360) {                   // W3: 8w, K=32, hi/lo cols, unscaled
        int e = tid - 139264;
        int j = e & 7, lane = (e >> 3) & 63, w = (e >> 9) & 7;
        int i16p = lane & 15, qp = lane >> 4;
        int k = w * 32 + qp * 8 + j;
        float wv = W3[k];
        unsigned short wh = f2bf(wv);
        unsigned short v = 0;
        if (i16p == 0) v = wh;
        else if (i16p == 1) v = f2bf(wv - bf2f(wh));
        wp[139264 + e] = v;
    }
    if (tid < 768) {
        int l = tid >> 8, n = tid & 255;
        const float* s = (l == 0) ? s0 : (l == 1 ? s1 : s2);
        const float* b = (l == 0) ? b0 : (l == 1 ? b1 : b2);
        float sv = s[n], bv = b[n];
        float sc = sqrtf(LOG2E / (2.0f * sv * sv));
        negc[l * 256 + n] = sc * bv;             // t_n
    }
}

constexpr int ROWS = 128;    // rows per block (two 64-row tiles)
constexpr int HSTR = 264;    // h row stride, bf16 elems (+8 pad; 528 B)
constexpr int ASTR = 40;     // A0 row stride (80 B)

// MFMA over one 64-row tile, this wave's 32 cols. acc[rg][ct] zero-inited.
template <int NKS, int SSTR>
__device__ __forceinline__ void mfma_tile(const unsigned short* __restrict__ src,
                                          const short8* __restrict__ wp8,
                                          f32x4 (&acc)[4][2], int i16, int q) {
#pragma unroll
    for (int rg = 0; rg < 4; ++rg)
#pragma unroll
        for (int ct = 0; ct < 2; ++ct)
            acc[rg][ct] = f32x4{0.f, 0.f, 0.f, 0.f};
    const unsigned short* abase = src + i16 * SSTR + q * 8;
#pragma unroll
    for (int ks = 0; ks < NKS; ++ks) {
        short8 a[4];
#pragma unroll
        for (int rg = 0; rg < 4; ++rg)
            a[rg] = *(const short8*)(abase + rg * 16 * SSTR + ks * 32);
#pragma unroll
        for (int ct = 0; ct < 2; ++ct) {
            short8 wf = wp8[(ks * 2 + ct) * 64];
#pragma unroll
            for (int rg = 0; rg < 4; ++rg)
                acc[rg][ct] = __builtin_amdgcn_mfma_f32_16x16x32_bf16(a[rg], wf, acc[rg][ct], 0, 0, 0);
        }
    }
}

// Gaussian activation + bf16 pack + b32 store of one tile's acc.
__device__ __forceinline__ void act_store(f32x4 (&acc)[4][2],
                                          const float* __restrict__ ncp,
                                          unsigned short* __restrict__ hdst,
                                          int cbase, int q) {
    const f32x2 T = *(const f32x2*)(ncp + cbase);
#pragma unroll
    for (int rg = 0; rg < 4; ++rg) {
        float g[4][2];
#pragma unroll
        for (int ct = 0; ct < 2; ++ct) {
            f32x2 tb = f32x2{T[ct], T[ct]};
            f32x2 ylo = pk_add2(f32x2{acc[rg][ct][0], acc[rg][ct][1]}, tb);
            f32x2 yhi = pk_add2(f32x2{acc[rg][ct][2], acc[rg][ct][3]}, tb);
            f32x2 wlo = pk_mul2(ylo, ylo);
            f32x2 whi = pk_mul2(yhi, yhi);
            g[0][ct] = __builtin_amdgcn_exp2f(-wlo[0]);
            g[1][ct] = __builtin_amdgcn_exp2f(-wlo[1]);
            g[2][ct] = __builtin_amdgcn_exp2f(-whi[0]);
            g[3][ct] = __builtin_amdgcn_exp2f(-whi[1]);
        }
#pragma unroll
        for (int rr = 0; rr < 4; ++rr)
            *(unsigned*)&hdst[(rg * 16 + q * 4 + rr) * HSTR + cbase] = pk_bf16(g[rr][0], g[rr][1]);
    }
}

__global__ __launch_bounds__(512, 4) void mlp_kernel(
    const float* __restrict__ pos,
    const float* __restrict__ b3,
    const unsigned short* __restrict__ Wp,
    const float* __restrict__ negc,
    float* __restrict__ out)
{
    __shared__ unsigned short hA[64 * HSTR];    // 33792 B
    __shared__ unsigned short hB[64 * HSTR];    // 33792 B
    __shared__ unsigned short A0[ROWS * ASTR];  // 10240 B (reused as f32 scr)

    const int tid  = threadIdx.x;
    const int lane = tid & 63;
    const int w    = tid >> 6;                  // wave 0..7 = col slice
    const int i16  = lane & 15, q = lane >> 4;
    const int cbase = w * 32 + 2 * i16;
    const long row0 = (long)blockIdx.x * ROWS;

    // ---- build A0 rows (both tiles): [p0h,p0h,p0l, p1h,p1h,p1l, p2h,p2h,p2l, 0..]
    if (tid < ROWS) {
        const float* pp = pos + (row0 + tid) * 3;
        float p0 = pp[0], p1 = pp[1], p2 = pp[2];
        short h0 = (short)f2bf(p0); short l0 = (short)f2bf(p0 - bf2f((unsigned short)h0));
        short h1 = (short)f2bf(p1); short l1 = (short)f2bf(p1 - bf2f((unsigned short)h1));
        short h2 = (short)f2bf(p2); short l2 = (short)f2bf(p2 - bf2f((unsigned short)h2));
        unsigned short* arow = A0 + tid * ASTR;
        *(short8*)(arow + 0)  = short8{h0, h0, l0, h1, h1, l1, h2, h2};
        *(short8*)(arow + 8)  = short8{l2, 0, 0, 0, 0, 0, 0, 0};
        *(short8*)(arow + 16) = short8{0, 0, 0, 0, 0, 0, 0, 0};
        *(short8*)(arow + 24) = short8{0, 0, 0, 0, 0, 0, 0, 0};
    }
    __syncthreads();

    f32x4 accA[4][2], accB[4][2];
    const short8* wp0 = (const short8*)Wp + (w * 2) * 64 + lane;
    const short8* wp1 = (const short8*)(Wp + 8192)  + (w * 16) * 64 + lane;
    const short8* wp2 = (const short8*)(Wp + 73728) + (w * 16) * 64 + lane;

    // R0: layer0 both tiles; act A
    mfma_tile<1, ASTR>(A0,             wp0, accA, i16, q);
    mfma_tile<1, ASTR>(A0 + 64 * ASTR, wp0, accB, i16, q);
    act_store(accA, negc, hA, cbase, q);
    __syncthreads();
    // R1: mfmaA(1) || actB(0)
    mfma_tile<8, HSTR>(hA, wp1, accA, i16, q);
    act_store(accB, negc, hB, cbase, q);
    __syncthreads();
    // R2: mfmaB(1) || actA(1)
    mfma_tile<8, HSTR>(hB, wp1, accB, i16, q);
    act_store(accA, negc + 256, hA, cbase, q);
    __syncthreads();
    // R3: mfmaA(2) || actB(1)
    mfma_tile<8, HSTR>(hA, wp2, accA, i16, q);
    act_store(accB, negc + 256, hB, cbase, q);
    __syncthreads();
    // R4: mfmaB(2) || actA(2)
    mfma_tile<8, HSTR>(hB, wp2, accB, i16, q);
    act_store(accA, negc + 512, hA, cbase, q);
    __syncthreads();

    // ---- layer 3: per-wave K-slice 32 via MFMA (hi/lo W3 in B-cols 0,1) ----
    const short8* w3p = (const short8*)(Wp + 139264) + w * 64 + lane;
    short8 wf3 = w3p[0];
    float* scrA = (float*)A0;          // 16 x 64 f32 = 4 KB
    float* scrB = scrA + 1024;         // next 4 KB
    f32x4 acc3A[4], acc3B[4];

    // R5: mfma3A || actB(2)
    {
        const unsigned short* ab3 = hA + i16 * HSTR + w * 32 + q * 8;
#pragma unroll
        for (int rg = 0; rg < 4; ++rg) {
            short8 a = *(const short8*)(ab3 + rg * 16 * HSTR);
            acc3A[rg] = __builtin_amdgcn_mfma_f32_16x16x32_bf16(a, wf3, f32x4{0.f,0.f,0.f,0.f}, 0, 0, 0);
        }
    }
    act_store(accB, negc + 512, hB, cbase, q);
    __syncthreads();
    // R6: mfma3B || scrA store
    {
        const unsigned short* ab3 = hB + i16 * HSTR + w * 32 + q * 8;
#pragma unroll
        for (int rg = 0; rg < 4; ++rg) {
            short8 a = *(const short8*)(ab3 + rg * 16 * HSTR);
            acc3B[rg] = __builtin_amdgcn_mfma_f32_16x16x32_bf16(a, wf3, f32x4{0.f,0.f,0.f,0.f}, 0, 0, 0);
        }
    }
    if (i16 < 2) {
#pragma unroll
        for (int rg = 0; rg < 4; ++rg)
            *(f32x4*)&scrA[(w * 2 + i16) * 64 + rg * 16 + q * 4] = acc3A[rg];
    }
    __syncthreads();
    // R7: reduceA || scrB store
    if (i16 < 2) {
#pragma unroll
        for (int rg = 0; rg < 4; ++rg)
            *(f32x4*)&scrB[(w * 2 + i16) * 64 + rg * 16 + q * 4] = acc3B[rg];
    }
    if (tid < 64) {
        float s = 0.f;
#pragma unroll
        for (int g = 0; g < 16; ++g) s += scrA[g * 64 + tid];
        float x  = s + b3[0];
        float xm = fminf(x, 8.0f);
        float e  = __builtin_amdgcn_exp2f(xm * LOG2E);
        float sp = __builtin_amdgcn_logf(1.0f + e) * LN2;
        out[row0 + tid] = (x > 8.0f) ? x : sp;
    }
    __syncthreads();
    // R8: reduceB
    if (tid < 64) {
        float s = 0.f;
#pragma unroll
        for (int g = 0; g < 16; ++g) s += scrB[g * 64 + tid];
        float x  = s + b3[0];
        float xm = fminf(x, 8.0f);
        float e  = __builtin_amdgcn_exp2f(xm * LOG2E);
        float sp = __builtin_amdgcn_logf(1.0f + e) * LN2;
        out[row0 + 64 + tid] = (x > 8.0f) ? x : sp;
    }
}

extern "C" void kernel_launch(void* const* d_in, const int* in_sizes, int n_in,
                              void* d_out, int out_size, void* d_ws, size_t ws_size,
                              hipStream_t stream) {
    const float* pos = (const float*)d_in[0];
    const float* W0  = (const float*)d_in[1];
    const float* b0  = (const float*)d_in[2];
    const float* W1  = (const float*)d_in[3];
    const float* b1  = (const float*)d_in[4];
    const float* W2  = (const float*)d_in[5];
    const float* b2  = (const float*)d_in[6];
    const float* W3  = (const float*)d_in[7];
    const float* b3  = (const float*)d_in[8];
    const float* s0  = (const float*)d_in[9];
    const float* s1  = (const float*)d_in[10];
    const float* s2  = (const float*)d_in[11];

    unsigned short* wp = (unsigned short*)d_ws;              // 143360 bf16
    float* negc = (float*)((char*)d_ws + 286720);            // 768 fp32: 3 x t[256]

    pack_kernel<<<560, 256, 0, stream>>>(W0, W1, W2, W3, s0, s1, s2, b0, b1, b2, wp, negc);

    int nrows = in_sizes[0] / 3;          // 1048576
    int nblk  = nrows / ROWS;             // 8192
    mlp_kernel<<<nblk, 512, 0, stream>>>(pos, b3, wp, negc,
                                         (float*)d_out);
}

// Round 9
// 393.888 us; speedup vs baseline: 1.2547x; 1.2547x over previous
//
#include <hip/hip_runtime.h>
#include <hip/hip_bf16.h>
#include <math.h>

typedef __attribute__((ext_vector_type(8))) short short8;
typedef __attribute__((ext_vector_type(4))) float f32x4;
typedef __attribute__((ext_vector_type(2))) float f32x2;
typedef __attribute__((ext_vector_type(2))) unsigned int uint2v;

#define LOG2E 1.4426950408889634f
#define LN2   0.6931471805599453f

__device__ __forceinline__ unsigned short f2bf(float f) {
    union { float f; unsigned u; } v; v.f = f;
    unsigned u = v.u;
    u += 0x7fffu + ((u >> 16) & 1u);   // RNE, finite
    return (unsigned short)(u >> 16);
}
__device__ __forceinline__ float bf2f(unsigned short h) {
    union { unsigned u; float f; } v; v.u = ((unsigned)h) << 16;
    return v.f;
}
__device__ __forceinline__ unsigned pk_bf16(float a, float b) {
    __hip_bfloat162 t = __float22bfloat162_rn(float2{a, b});   // v_cvt_pk_bf16_f32
    union { __hip_bfloat162 b; unsigned u; } v; v.b = t;
    return v.u;
}
// packed FP32 ops (VOP3P, CDNA2+)
__device__ __forceinline__ f32x2 pk_add2(f32x2 a, f32x2 b) {
    f32x2 d;
    asm("v_pk_add_f32 %0, %1, %2" : "=v"(d) : "v"(a), "v"(b));
    return d;
}
__device__ __forceinline__ f32x2 pk_mul2(f32x2 a, f32x2 b) {
    f32x2 d;
    asm("v_pk_mul_f32 %0, %1, %2" : "=v"(d) : "v"(a), "v"(b));
    return d;
}

// ---------------------------------------------------------------------------
// R9 STRUCTURE: 512-thread block, 8 waves, 128 rows = two 64-row tiles.
// Waves 0-3 = group A (tile A), waves 4-7 = group B (tile B). Each wave:
// R6's exact per-wave job (64 rows x 64 cols, acc[4][4] = 64 AGPR, ~64
// VGPR) -- R8's spill came from 2 acc sets per wave; this keeps ONE.
// Groups run the SAME pipeline offset by one phase; wave w and w+4 share a
// SIMD (round-robin), so each region deterministically pairs an MFMA-phase
// wave with an act-phase wave per SIMD -> MFMA||VALU overlap (fix for
// MfmaUtil+VALUBusy ~= 95% serial-phase signature). setprio (T5) now has a
// real role-split to arbitrate.
//   R0: m0(A)            R1: a0(A)||m0(B)   R2: m1(A)||a0(B)
//   R3: a1(A)||m1(B)     R4: m2(A)||a1(B)   R5: a2(A)||m2(B)
//   R6: m3+scrA(A)||a2(B)  R7: redA||m3+scrB(B)  R8: redB
// Hazards: act(X,l) overwrites hX read by mfma(X,l) one region earlier ->
// region barrier covers. Groups touch disjoint buffers; scrB overlays hA
// (last hA read = R6).
// Pack layout: IDENTICAL to R5/R6 (verified): wave-slice w4 = wave&3 owns
// cols [w4*64, +64), streams at Wp(+8192/+73728), W3 hi/lo at +139264.
// SCALE FOLD as R5/R6: s_n folded into W, t_n = s_n*b_n in negc.
// LDS: hA+hB+A0 = 33792*2+10240 = 77824 -> 2 blocks/CU (16 waves/CU,
// 4/SIMD). __launch_bounds__(512,4) pins <=128 regs/wave (R2/R8 lesson:
// 64 AGPR acc + <=64 VGPR; crossing 128 = cliff or spill).
// ---------------------------------------------------------------------------
__global__ void pack_kernel(const float* __restrict__ W0, const float* __restrict__ W1,
                            const float* __restrict__ W2, const float* __restrict__ W3,
                            const float* __restrict__ s0, const float* __restrict__ s1,
                            const float* __restrict__ s2,
                            const float* __restrict__ b0, const float* __restrict__ b1,
                            const float* __restrict__ b2,
                            unsigned short* __restrict__ wp, float* __restrict__ negc) {
    int tid = blockIdx.x * 256 + threadIdx.x;    // 0 .. 143359
    if (tid < 8192) {                            // W0 (NKS=1), scaled hi/lo
        int j = tid & 7, lane = (tid >> 3) & 63, ct = (tid >> 9) & 3, w = tid >> 11;
        int k = ((lane >> 4) * 8) + j;           // 0..31
        int n = w * 64 + 4 * (lane & 15) + ct;
        unsigned short v = 0;
        if (k < 9) {
            int d = k / 3, m = k - d * 3;        // m: 0->wh 1->wl 2->wh
            float sv = s0[n];
            float sc = sqrtf(LOG2E / (2.0f * sv * sv));
            float wv = W0[d * 256 + n] * sc;
            unsigned short wh = f2bf(wv);
            v = (m == 1) ? f2bf(wv - bf2f(wh)) : wh;
        }
        wp[tid] = v;
    } else if (tid < 139264) {                   // W1 / W2 (NKS=8), scaled
        int e = tid - 8192;
        const float* W = W1;
        const float* S = s1;
        if (e >= 65536) { W = W2; S = s2; e -= 65536; }
        int j = e & 7, lane = (e >> 3) & 63, ct = (e >> 9) & 3, ks = (e >> 11) & 7, w = e >> 14;
        int k = ks * 32 + ((lane >> 4) * 8) + j;
        int n = w * 64 + 4 * (lane & 15) + ct;
        float sv = S[n];
        float sc = sqrtf(LOG2E / (2.0f * sv * sv));
        wp[tid] = f2bf(W[k * 256 + n] * sc);     // full-offset store
    } else if (tid < 143360) {                   // W3 hi/lo (2 B-cols), unscaled
        int e = tid - 139264;
        int j = e & 7, lane = (e >> 3) & 63, ks = (e >> 9) & 1, w = e >> 10;
        int i16p = lane & 15, qp = lane >> 4;
        int k = w * 64 + ks * 32 + qp * 8 + j;
        float wv = W3[k];
        unsigned short wh = f2bf(wv);
        unsigned short v = 0;
        if (i16p == 0) v = wh;
        else if (i16p == 1) v = f2bf(wv - bf2f(wh));
        wp[139264 + e] = v;
    }
    if (tid < 768) {
        int l = tid >> 8, n = tid & 255;
        const float* s = (l == 0) ? s0 : (l == 1 ? s1 : s2);
        const float* b = (l == 0) ? b0 : (l == 1 ? b1 : b2);
        float sv = s[n], bv = b[n];
        float sc = sqrtf(LOG2E / (2.0f * sv * sv));
        negc[l * 256 + n] = sc * bv;             // t_n
    }
}

constexpr int HSTR = 264;    // h row stride, bf16 elems (+8 pad; 528 B)
constexpr int ASTR = 40;     // A0 row stride (80 B)

// MFMA over one 64-row tile, this wave's 64 cols (R6's layer, MFMA part).
template <int NKS, int SSTR>
__device__ __forceinline__ void mfma_l(const unsigned short* __restrict__ src,
                                       const short8* __restrict__ wp8,
                                       f32x4 (&acc)[4][4], int i16, int q) {
#pragma unroll
    for (int rg = 0; rg < 4; ++rg)
#pragma unroll
        for (int ct = 0; ct < 4; ++ct)
            acc[rg][ct] = f32x4{0.f, 0.f, 0.f, 0.f};
    const unsigned short* abase = src + i16 * SSTR + q * 8;
    __builtin_amdgcn_s_setprio(1);   // T5: MFMA-phase wave wins arbitration
#pragma unroll
    for (int ks = 0; ks < NKS; ++ks) {
        short8 a[4];
#pragma unroll
        for (int rg = 0; rg < 4; ++rg)
            a[rg] = *(const short8*)(abase + rg * 16 * SSTR + ks * 32);
#pragma unroll
        for (int ct = 0; ct < 4; ++ct) {
            short8 wf = wp8[(ks * 4 + ct) * 64];
#pragma unroll
            for (int rg = 0; rg < 4; ++rg)
                acc[rg][ct] = __builtin_amdgcn_mfma_f32_16x16x32_bf16(a[rg], wf, acc[rg][ct], 0, 0, 0);
        }
    }
    __builtin_amdgcn_s_setprio(0);
}

// Gaussian activation + bf16 pack + b64 store (R6's layer, act part).
__device__ __forceinline__ void act_store4(f32x4 (&acc)[4][4],
                                           const float* __restrict__ ncp,
                                           unsigned short* __restrict__ hdst,
                                           int ce, int q) {
    const f32x4 T = *(const f32x4*)(ncp + ce);
    f32x2 tb[4];
#pragma unroll
    for (int ct = 0; ct < 4; ++ct) tb[ct] = f32x2{T[ct], T[ct]};
#pragma unroll
    for (int rg = 0; rg < 4; ++rg) {
        float gg[4][4];   // [rr][ct]
#pragma unroll
        for (int ct = 0; ct < 4; ++ct) {
            f32x2 xlo = f32x2{acc[rg][ct][0], acc[rg][ct][1]};
            f32x2 xhi = f32x2{acc[rg][ct][2], acc[rg][ct][3]};
            f32x2 ylo = pk_add2(xlo, tb[ct]);
            f32x2 yhi = pk_add2(xhi, tb[ct]);
            f32x2 wlo = pk_mul2(ylo, ylo);
            f32x2 whi = pk_mul2(yhi, yhi);
            gg[0][ct] = __builtin_amdgcn_exp2f(-wlo[0]);
            gg[1][ct] = __builtin_amdgcn_exp2f(-wlo[1]);
            gg[2][ct] = __builtin_amdgcn_exp2f(-whi[0]);
            gg[3][ct] = __builtin_amdgcn_exp2f(-whi[1]);
        }
#pragma unroll
        for (int rr = 0; rr < 4; ++rr) {
            uint2v v;
            v[0] = pk_bf16(gg[rr][0], gg[rr][1]);
            v[1] = pk_bf16(gg[rr][2], gg[rr][3]);
            *(uint2v*)&hdst[(rg * 16 + q * 4 + rr) * HSTR + ce] = v;
        }
    }
}

// Layer-3 K-slice MFMA (R6's verified epilogue, per 64-row tile).
__device__ __forceinline__ void l3_mfma(const unsigned short* __restrict__ ab3,
                                        const short8* __restrict__ w3p,
                                        f32x4 (&acc3)[4]) {
#pragma unroll
    for (int rg = 0; rg < 4; ++rg) acc3[rg] = f32x4{0.f, 0.f, 0.f, 0.f};
    __builtin_amdgcn_s_setprio(1);
#pragma unroll
    for (int ks = 0; ks < 2; ++ks) {
        short8 wf = w3p[ks * 64];
#pragma unroll
        for (int rg = 0; rg < 4; ++rg) {
            short8 a = *(const short8*)(ab3 + rg * 16 * HSTR + ks * 32);
            acc3[rg] = __builtin_amdgcn_mfma_f32_16x16x32_bf16(a, wf, acc3[rg], 0, 0, 0);
        }
    }
    __builtin_amdgcn_s_setprio(0);
}

__global__ __launch_bounds__(512, 4) void mlp_kernel(
    const float* __restrict__ pos,
    const float* __restrict__ b3,
    const unsigned short* __restrict__ Wp,
    const float* __restrict__ negc,
    float* __restrict__ out)
{
    __shared__ unsigned short hA[64 * HSTR];    // 33792 B (tile A)
    __shared__ unsigned short hB[64 * HSTR];    // 33792 B (tile B)
    __shared__ unsigned short A0[128 * ASTR];   // 10240 B (also scrA)

    const int tid  = threadIdx.x;
    const int lane = tid & 63;
    const int wave = tid >> 6;
    const int w4   = wave & 3;                  // col slice within group
    const int grp  = wave >> 2;                 // 0 = tile A, 1 = tile B
    const int i16  = lane & 15, q = lane >> 4;
    const int ce   = w4 * 64 + 4 * i16;
    const long row0 = (long)blockIdx.x * 128;

    // ---- build A0 rows 0..127: [p0h,p0h,p0l, p1h,p1h,p1l, p2h,p2h,p2l, 0..]
    if (tid < 128) {
        const float* pp = pos + (row0 + tid) * 3;
        float p0 = pp[0], p1 = pp[1], p2 = pp[2];
        short h0 = (short)f2bf(p0); short l0 = (short)f2bf(p0 - bf2f((unsigned short)h0));
        short h1 = (short)f2bf(p1); short l1 = (short)f2bf(p1 - bf2f((unsigned short)h1));
        short h2 = (short)f2bf(p2); short l2 = (short)f2bf(p2 - bf2f((unsigned short)h2));
        unsigned short* arow = A0 + tid * ASTR;
        *(short8*)(arow + 0)  = short8{h0, h0, l0, h1, h1, l1, h2, h2};
        *(short8*)(arow + 8)  = short8{l2, 0, 0, 0, 0, 0, 0, 0};
        *(short8*)(arow + 16) = short8{0, 0, 0, 0, 0, 0, 0, 0};
        *(short8*)(arow + 24) = short8{0, 0, 0, 0, 0, 0, 0, 0};
    }
    __syncthreads();

    f32x4 acc[4][4];
    const short8* wp0 = (const short8*)Wp            + (w4 * 4)  * 64 + lane;
    const short8* wp1 = (const short8*)(Wp + 8192)   + (w4 * 32) * 64 + lane;
    const short8* wp2 = (const short8*)(Wp + 73728)  + (w4 * 32) * 64 + lane;
    const short8* w3p = (const short8*)(Wp + 139264) + (w4 * 2)  * 64 + lane;

    // R0: m0(A)
    if (!grp) mfma_l<1, ASTR>(A0, wp0, acc, i16, q);
    __syncthreads();
    // R1: a0(A) || m0(B)
    if (!grp) act_store4(acc, negc, hA, ce, q);
    else      mfma_l<1, ASTR>(A0 + 64 * ASTR, wp0, acc, i16, q);
    __syncthreads();
    // R2: m1(A) || a0(B)
    if (!grp) mfma_l<8, HSTR>(hA, wp1, acc, i16, q);
    else      act_store4(acc, negc, hB, ce, q);
    __syncthreads();
    // R3: a1(A) || m1(B)
    if (!grp) act_store4(acc, negc + 256, hA, ce, q);
    else      mfma_l<8, HSTR>(hB, wp1, acc, i16, q);
    __syncthreads();
    // R4: m2(A) || a1(B)
    if (!grp) mfma_l<8, HSTR>(hA, wp2, acc, i16, q);
    else      act_store4(acc, negc + 256, hB, ce, q);
    __syncthreads();
    // R5: a2(A) || m2(B)
    if (!grp) act_store4(acc, negc + 512, hA, ce, q);
    else      mfma_l<8, HSTR>(hB, wp2, acc, i16, q);
    __syncthreads();

    f32x4 acc3[4];
    float* scrA = (float*)A0;    // 8 seg x 64 f32 = 2 KB
    float* scrB = (float*)hA;    // overlays hA (last read R6)

    // R6: m3(A)+scrA || a2(B)
    if (!grp) {
        l3_mfma(hA + i16 * HSTR + w4 * 64 + q * 8, w3p, acc3);
        if (i16 < 2) {
#pragma unroll
            for (int rg = 0; rg < 4; ++rg)
                *(f32x4*)&scrA[(w4 * 2 + i16) * 64 + rg * 16 + q * 4] = acc3[rg];
        }
    } else {
        act_store4(acc, negc + 512, hB, ce, q);
    }
    __syncthreads();
    // R7: reduceA || m3(B)+scrB
    if (grp) {
        l3_mfma(hB + i16 * HSTR + w4 * 64 + q * 8, w3p, acc3);
        if (i16 < 2) {
#pragma unroll
            for (int rg = 0; rg < 4; ++rg)
                *(f32x4*)&scrB[(w4 * 2 + i16) * 64 + rg * 16 + q * 4] = acc3[rg];
        }
    } else if (tid < 64) {
        float s = 0.f;
#pragma unroll
        for (int g = 0; g < 8; ++g) s += scrA[g * 64 + tid];
        float x  = s + b3[0];
        float xm = fminf(x, 8.0f);
        float e  = __builtin_amdgcn_exp2f(xm * LOG2E);
        float sp = __builtin_amdgcn_logf(1.0f + e) * LN2;
        out[row0 + tid] = (x > 8.0f) ? x : sp;
    }
    __syncthreads();
    // R8: reduceB
    if (tid >= 256 && tid < 320) {
        int r = tid & 63;
        float s = 0.f;
#pragma unroll
        for (int g = 0; g < 8; ++g) s += scrB[g * 64 + r];
        float x  = s + b3[0];
        float xm = fminf(x, 8.0f);
        float e  = __builtin_amdgcn_exp2f(xm * LOG2E);
        float sp = __builtin_amdgcn_logf(1.0f + e) * LN2;
        out[row0 + 64 + r] = (x > 8.0f) ? x : sp;
    }
}

extern "C" void kernel_launch(void* const* d_in, const int* in_sizes, int n_in,
                              void* d_out, int out_size, void* d_ws, size_t ws_size,
                              hipStream_t stream) {
    const float* pos = (const float*)d_in[0];
    const float* W0  = (const float*)d_in[1];
    const float* b0  = (const float*)d_in[2];
    const float* W1  = (const float*)d_in[3];
    const float* b1  = (const float*)d_in[4];
    const float* W2  = (const float*)d_in[5];
    const float* b2  = (const float*)d_in[6];
    const float* W3  = (const float*)d_in[7];
    const float* b3  = (const float*)d_in[8];
    const float* s0  = (const float*)d_in[9];
    const float* s1  = (const float*)d_in[10];
    const float* s2  = (const float*)d_in[11];

    unsigned short* wp = (unsigned short*)d_ws;              // 143360 bf16
    float* negc = (float*)((char*)d_ws + 286720);            // 768 fp32: 3 x t[256]

    pack_kernel<<<560, 256, 0, stream>>>(W0, W1, W2, W3, s0, s1, s2, b0, b1, b2, wp, negc);

    int nrows = in_sizes[0] / 3;          // 1048576
    int nblk  = nrows / 128;              // 8192
    mlp_kernel<<<nblk, 512, 0, stream>>>(pos, b3, wp, negc,
                                         (float*)d_out);
}

// Round 10
// 391.367 us; speedup vs baseline: 1.2628x; 1.0064x over previous
//
#include <hip/hip_runtime.h>
#include <hip/hip_bf16.h>
#include <math.h>

typedef __attribute__((ext_vector_type(8))) short short8;
typedef __attribute__((ext_vector_type(4))) float f32x4;
typedef __attribute__((ext_vector_type(2))) float f32x2;
typedef __attribute__((ext_vector_type(2))) unsigned int uint2v;

#define LOG2E 1.4426950408889634f
#define LN2   0.6931471805599453f

__device__ __forceinline__ unsigned short f2bf(float f) {
    union { float f; unsigned u; } v; v.f = f;
    unsigned u = v.u;
    u += 0x7fffu + ((u >> 16) & 1u);   // RNE, finite
    return (unsigned short)(u >> 16);
}
__device__ __forceinline__ float bf2f(unsigned short h) {
    union { unsigned u; float f; } v; v.u = ((unsigned)h) << 16;
    return v.f;
}
__device__ __forceinline__ unsigned pk_bf16(float a, float b) {
    __hip_bfloat162 t = __float22bfloat162_rn(float2{a, b});   // v_cvt_pk_bf16_f32
    union { __hip_bfloat162 b; unsigned u; } v; v.b = t;
    return v.u;
}
// packed FP32 ops (VOP3P, CDNA2+)
__device__ __forceinline__ f32x2 pk_add2(f32x2 a, f32x2 b) {
    f32x2 d;
    asm("v_pk_add_f32 %0, %1, %2" : "=v"(d) : "v"(a), "v"(b));
    return d;
}
__device__ __forceinline__ f32x2 pk_mul2(f32x2 a, f32x2 b) {
    f32x2 d;
    asm("v_pk_mul_f32 %0, %1, %2" : "=v"(d) : "v"(a), "v"(b));
    return d;
}

// ---------------------------------------------------------------------------
// R10 = R9 with ASSIGNMENT-PROOF group pairing.
// R9's regression (sum MfmaUtil+VALUBusy 95 -> 83) is consistent with
// chunked wave->SIMD assignment: grp = wave>>2 put both co-resident waves
// of a SIMD in the SAME role -> serial phases + 9 barriers. Fix:
//   grp = (wave ^ (wave>>2)) & 1   (A = {0,2,5,7}, B = {1,3,4,6})
//   w4  = wave >> 1                (each group covers slices 0..3)
// Under round-robin (pairs w,w+4: bit2 flips) AND chunked (pairs 2k,2k+1:
// bit0 flips) assignment, every SIMD hosts one MFMA-role + one act-role
// wave per region -> m114 co-schedule regime; setprio (T5) arbitrates a
// real role split.
// Everything else identical to R9 (passed, no spill):
//   512 threads, two 64-row tiles, regions
//   R0: m0(A)            R1: a0(A)||m0(B)   R2: m1(A)||a0(B)
//   R3: a1(A)||m1(B)     R4: m2(A)||a1(B)   R5: a2(A)||m2(B)
//   R6: m3+scrA(A)||a2(B)  R7: redA||m3+scrB(B)  R8: redB
// Pack layout / scale-fold identical to R5/R6 (verified).
// Register budget: 64 AGPR acc + <=64 VGPR <= 128 (R2/R8 lessons).
// PRE-COMMITTED: if dur >= 326us or sum <= 95 -> revert to R6, declare
// serial-phase roofline.
// ---------------------------------------------------------------------------
__global__ void pack_kernel(const float* __restrict__ W0, const float* __restrict__ W1,
                            const float* __restrict__ W2, const float* __restrict__ W3,
                            const float* __restrict__ s0, const float* __restrict__ s1,
                            const float* __restrict__ s2,
                            const float* __restrict__ b0, const float* __restrict__ b1,
                            const float* __restrict__ b2,
                            unsigned short* __restrict__ wp, float* __restrict__ negc) {
    int tid = blockIdx.x * 256 + threadIdx.x;    // 0 .. 143359
    if (tid < 8192) {                            // W0 (NKS=1), scaled hi/lo
        int j = tid & 7, lane = (tid >> 3) & 63, ct = (tid >> 9) & 3, w = tid >> 11;
        int k = ((lane >> 4) * 8) + j;           // 0..31
        int n = w * 64 + 4 * (lane & 15) + ct;
        unsigned short v = 0;
        if (k < 9) {
            int d = k / 3, m = k - d * 3;        // m: 0->wh 1->wl 2->wh
            float sv = s0[n];
            float sc = sqrtf(LOG2E / (2.0f * sv * sv));
            float wv = W0[d * 256 + n] * sc;
            unsigned short wh = f2bf(wv);
            v = (m == 1) ? f2bf(wv - bf2f(wh)) : wh;
        }
        wp[tid] = v;
    } else if (tid < 139264) {                   // W1 / W2 (NKS=8), scaled
        int e = tid - 8192;
        const float* W = W1;
        const float* S = s1;
        if (e >= 65536) { W = W2; S = s2; e -= 65536; }
        int j = e & 7, lane = (e >> 3) & 63, ct = (e >> 9) & 3, ks = (e >> 11) & 7, w = e >> 14;
        int k = ks * 32 + ((lane >> 4) * 8) + j;
        int n = w * 64 + 4 * (lane & 15) + ct;
        float sv = S[n];
        float sc = sqrtf(LOG2E / (2.0f * sv * sv));
        wp[tid] = f2bf(W[k * 256 + n] * sc);     // full-offset store
    } else if (tid < 143360) {                   // W3 hi/lo (2 B-cols), unscaled
        int e = tid - 139264;
        int j = e & 7, lane = (e >> 3) & 63, ks = (e >> 9) & 1, w = e >> 10;
        int i16p = lane & 15, qp = lane >> 4;
        int k = w * 64 + ks * 32 + qp * 8 + j;
        float wv = W3[k];
        unsigned short wh = f2bf(wv);
        unsigned short v = 0;
        if (i16p == 0) v = wh;
        else if (i16p == 1) v = f2bf(wv - bf2f(wh));
        wp[139264 + e] = v;
    }
    if (tid < 768) {
        int l = tid >> 8, n = tid & 255;
        const float* s = (l == 0) ? s0 : (l == 1 ? s1 : s2);
        const float* b = (l == 0) ? b0 : (l == 1 ? b1 : b2);
        float sv = s[n], bv = b[n];
        float sc = sqrtf(LOG2E / (2.0f * sv * sv));
        negc[l * 256 + n] = sc * bv;             // t_n
    }
}

constexpr int HSTR = 264;    // h row stride, bf16 elems (+8 pad; 528 B)
constexpr int ASTR = 40;     // A0 row stride (80 B)

// MFMA over one 64-row tile, this wave's 64 cols.
template <int NKS, int SSTR>
__device__ __forceinline__ void mfma_l(const unsigned short* __restrict__ src,
                                       const short8* __restrict__ wp8,
                                       f32x4 (&acc)[4][4], int i16, int q) {
#pragma unroll
    for (int rg = 0; rg < 4; ++rg)
#pragma unroll
        for (int ct = 0; ct < 4; ++ct)
            acc[rg][ct] = f32x4{0.f, 0.f, 0.f, 0.f};
    const unsigned short* abase = src + i16 * SSTR + q * 8;
    __builtin_amdgcn_s_setprio(1);   // T5: MFMA-role wave wins arbitration
#pragma unroll
    for (int ks = 0; ks < NKS; ++ks) {
        short8 a[4];
#pragma unroll
        for (int rg = 0; rg < 4; ++rg)
            a[rg] = *(const short8*)(abase + rg * 16 * SSTR + ks * 32);
#pragma unroll
        for (int ct = 0; ct < 4; ++ct) {
            short8 wf = wp8[(ks * 4 + ct) * 64];
#pragma unroll
            for (int rg = 0; rg < 4; ++rg)
                acc[rg][ct] = __builtin_amdgcn_mfma_f32_16x16x32_bf16(a[rg], wf, acc[rg][ct], 0, 0, 0);
        }
    }
    __builtin_amdgcn_s_setprio(0);
}

// Gaussian activation + bf16 pack + b64 store.
__device__ __forceinline__ void act_store4(f32x4 (&acc)[4][4],
                                           const float* __restrict__ ncp,
                                           unsigned short* __restrict__ hdst,
                                           int ce, int q) {
    const f32x4 T = *(const f32x4*)(ncp + ce);
    f32x2 tb[4];
#pragma unroll
    for (int ct = 0; ct < 4; ++ct) tb[ct] = f32x2{T[ct], T[ct]};
#pragma unroll
    for (int rg = 0; rg < 4; ++rg) {
        float gg[4][4];   // [rr][ct]
#pragma unroll
        for (int ct = 0; ct < 4; ++ct) {
            f32x2 xlo = f32x2{acc[rg][ct][0], acc[rg][ct][1]};
            f32x2 xhi = f32x2{acc[rg][ct][2], acc[rg][ct][3]};
            f32x2 ylo = pk_add2(xlo, tb[ct]);
            f32x2 yhi = pk_add2(xhi, tb[ct]);
            f32x2 wlo = pk_mul2(ylo, ylo);
            f32x2 whi = pk_mul2(yhi, yhi);
            gg[0][ct] = __builtin_amdgcn_exp2f(-wlo[0]);
            gg[1][ct] = __builtin_amdgcn_exp2f(-wlo[1]);
            gg[2][ct] = __builtin_amdgcn_exp2f(-whi[0]);
            gg[3][ct] = __builtin_amdgcn_exp2f(-whi[1]);
        }
#pragma unroll
        for (int rr = 0; rr < 4; ++rr) {
            uint2v v;
            v[0] = pk_bf16(gg[rr][0], gg[rr][1]);
            v[1] = pk_bf16(gg[rr][2], gg[rr][3]);
            *(uint2v*)&hdst[(rg * 16 + q * 4 + rr) * HSTR + ce] = v;
        }
    }
}

// Layer-3 K-slice MFMA (hi/lo W3 in B-cols 0,1).
__device__ __forceinline__ void l3_mfma(const unsigned short* __restrict__ ab3,
                                        const short8* __restrict__ w3p,
                                        f32x4 (&acc3)[4]) {
#pragma unroll
    for (int rg = 0; rg < 4; ++rg) acc3[rg] = f32x4{0.f, 0.f, 0.f, 0.f};
    __builtin_amdgcn_s_setprio(1);
#pragma unroll
    for (int ks = 0; ks < 2; ++ks) {
        short8 wf = w3p[ks * 64];
#pragma unroll
        for (int rg = 0; rg < 4; ++rg) {
            short8 a = *(const short8*)(ab3 + rg * 16 * HSTR + ks * 32);
            acc3[rg] = __builtin_amdgcn_mfma_f32_16x16x32_bf16(a, wf, acc3[rg], 0, 0, 0);
        }
    }
    __builtin_amdgcn_s_setprio(0);
}

__global__ __launch_bounds__(512, 4) void mlp_kernel(
    const float* __restrict__ pos,
    const float* __restrict__ b3,
    const unsigned short* __restrict__ Wp,
    const float* __restrict__ negc,
    float* __restrict__ out)
{
    __shared__ unsigned short hA[64 * HSTR];    // 33792 B (tile A)
    __shared__ unsigned short hB[64 * HSTR];    // 33792 B (tile B)
    __shared__ unsigned short A0[128 * ASTR];   // 10240 B (also scrA)

    const int tid  = threadIdx.x;
    const int lane = tid & 63;
    const int wave = tid >> 6;
    // assignment-proof role split: co-resident wave pairs differ in grp
    // under BOTH round-robin (w,w+4) and chunked (2k,2k+1) wave->SIMD maps.
    const int grp  = (wave ^ (wave >> 2)) & 1;  // 0 = tile A, 1 = tile B
    const int w4   = wave >> 1;                 // col slice within group
    const int i16  = lane & 15, q = lane >> 4;
    const int ce   = w4 * 64 + 4 * i16;
    const long row0 = (long)blockIdx.x * 128;

    // ---- build A0 rows 0..127: [p0h,p0h,p0l, p1h,p1h,p1l, p2h,p2h,p2l, 0..]
    if (tid < 128) {
        const float* pp = pos + (row0 + tid) * 3;
        float p0 = pp[0], p1 = pp[1], p2 = pp[2];
        short h0 = (short)f2bf(p0); short l0 = (short)f2bf(p0 - bf2f((unsigned short)h0));
        short h1 = (short)f2bf(p1); short l1 = (short)f2bf(p1 - bf2f((unsigned short)h1));
        short h2 = (short)f2bf(p2); short l2 = (short)f2bf(p2 - bf2f((unsigned short)h2));
        unsigned short* arow = A0 + tid * ASTR;
        *(short8*)(arow + 0)  = short8{h0, h0, l0, h1, h1, l1, h2, h2};
        *(short8*)(arow + 8)  = short8{l2, 0, 0, 0, 0, 0, 0, 0};
        *(short8*)(arow + 16) = short8{0, 0, 0, 0, 0, 0, 0, 0};
        *(short8*)(arow + 24) = short8{0, 0, 0, 0, 0, 0, 0, 0};
    }
    __syncthreads();

    f32x4 acc[4][4];
    const short8* wp0 = (const short8*)Wp            + (w4 * 4)  * 64 + lane;
    const short8* wp1 = (const short8*)(Wp + 8192)   + (w4 * 32) * 64 + lane;
    const short8* wp2 = (const short8*)(Wp + 73728)  + (w4 * 32) * 64 + lane;
    const short8* w3p = (const short8*)(Wp + 139264) + (w4 * 2)  * 64 + lane;

    // R0: m0(A)
    if (!grp) mfma_l<1, ASTR>(A0, wp0, acc, i16, q);
    __syncthreads();
    // R1: a0(A) || m0(B)
    if (!grp) act_store4(acc, negc, hA, ce, q);
    else      mfma_l<1, ASTR>(A0 + 64 * ASTR, wp0, acc, i16, q);
    __syncthreads();
    // R2: m1(A) || a0(B)
    if (!grp) mfma_l<8, HSTR>(hA, wp1, acc, i16, q);
    else      act_store4(acc, negc, hB, ce, q);
    __syncthreads();
    // R3: a1(A) || m1(B)
    if (!grp) act_store4(acc, negc + 256, hA, ce, q);
    else      mfma_l<8, HSTR>(hB, wp1, acc, i16, q);
    __syncthreads();
    // R4: m2(A) || a1(B)
    if (!grp) mfma_l<8, HSTR>(hA, wp2, acc, i16, q);
    else      act_store4(acc, negc + 256, hB, ce, q);
    __syncthreads();
    // R5: a2(A) || m2(B)
    if (!grp) act_store4(acc, negc + 512, hA, ce, q);
    else      mfma_l<8, HSTR>(hB, wp2, acc, i16, q);
    __syncthreads();

    f32x4 acc3[4];
    float* scrA = (float*)A0;    // 8 seg x 64 f32 = 2 KB
    float* scrB = (float*)hA;    // overlays hA (last read R6)

    // R6: m3(A)+scrA || a2(B)
    if (!grp) {
        l3_mfma(hA + i16 * HSTR + w4 * 64 + q * 8, w3p, acc3);
        if (i16 < 2) {
#pragma unroll
            for (int rg = 0; rg < 4; ++rg)
                *(f32x4*)&scrA[(w4 * 2 + i16) * 64 + rg * 16 + q * 4] = acc3[rg];
        }
    } else {
        act_store4(acc, negc + 512, hB, ce, q);
    }
    __syncthreads();
    // R7: reduceA || m3(B)+scrB
    if (grp) {
        l3_mfma(hB + i16 * HSTR + w4 * 64 + q * 8, w3p, acc3);
        if (i16 < 2) {
#pragma unroll
            for (int rg = 0; rg < 4; ++rg)
                *(f32x4*)&scrB[(w4 * 2 + i16) * 64 + rg * 16 + q * 4] = acc3[rg];
        }
    } else if (tid < 64) {       // wave 0: grp(0)=0 -> in the A-branch else
        float s = 0.f;
#pragma unroll
        for (int g = 0; g < 8; ++g) s += scrA[g * 64 + tid];
        float x  = s + b3[0];
        float xm = fminf(x, 8.0f);
        float e  = __builtin_amdgcn_exp2f(xm * LOG2E);
        float sp = __builtin_amdgcn_logf(1.0f + e) * LN2;
        out[row0 + tid] = (x > 8.0f) ? x : sp;
    }
    __syncthreads();
    // R8: reduceB (wave 4, group-agnostic: reads scrB written in R7)
    if (tid >= 256 && tid < 320) {
        int r = tid & 63;
        float s = 0.f;
#pragma unroll
        for (int g = 0; g < 8; ++g) s += scrB[g * 64 + r];
        float x  = s + b3[0];
        float xm = fminf(x, 8.0f);
        float e  = __builtin_amdgcn_exp2f(xm * LOG2E);
        float sp = __builtin_amdgcn_logf(1.0f + e) * LN2;
        out[row0 + 64 + r] = (x > 8.0f) ? x : sp;
    }
}

extern "C" void kernel_launch(void* const* d_in, const int* in_sizes, int n_in,
                              void* d_out, int out_size, void* d_ws, size_t ws_size,
                              hipStream_t stream) {
    const float* pos = (const float*)d_in[0];
    const float* W0  = (const float*)d_in[1];
    const float* b0  = (const float*)d_in[2];
    const float* W1  = (const float*)d_in[3];
    const float* b1  = (const float*)d_in[4];
    const float* W2  = (const float*)d_in[5];
    const float* b2  = (const float*)d_in[6];
    const float* W3  = (const float*)d_in[7];
    const float* b3  = (const float*)d_in[8];
    const float* s0  = (const float*)d_in[9];
    const float* s1  = (const float*)d_in[10];
    const float* s2  = (const float*)d_in[11];

    unsigned short* wp = (unsigned short*)d_ws;              // 143360 bf16
    float* negc = (float*)((char*)d_ws + 286720);            // 768 fp32: 3 x t[256]

    pack_kernel<<<560, 256, 0, stream>>>(W0, W1, W2, W3, s0, s1, s2, b0, b1, b2, wp, negc);

    int nrows = in_sizes[0] / 3;          // 1048576
    int nblk  = nrows / 128;              // 8192
    mlp_kernel<<<nblk, 512, 0, stream>>>(pos, b3, wp, negc,
                                         (float*)d_out);
}

// Round 11
// 379.455 us; speedup vs baseline: 1.3024x; 1.0314x over previous
//
#include <hip/hip_runtime.h>
#include <hip/hip_bf16.h>
#include <math.h>

typedef __attribute__((ext_vector_type(8))) short short8;
typedef __attribute__((ext_vector_type(4))) float f32x4;
typedef __attribute__((ext_vector_type(2))) float f32x2;
typedef __attribute__((ext_vector_type(2))) unsigned int uint2v;

#define LOG2E 1.4426950408889634f
#define LN2   0.6931471805599453f

__device__ __forceinline__ unsigned short f2bf(float f) {
    union { float f; unsigned u; } v; v.f = f;
    unsigned u = v.u;
    u += 0x7fffu + ((u >> 16) & 1u);   // RNE, finite
    return (unsigned short)(u >> 16);
}
__device__ __forceinline__ float bf2f(unsigned short h) {
    union { unsigned u; float f; } v; v.u = ((unsigned)h) << 16;
    return v.f;
}
__device__ __forceinline__ unsigned pk_bf16(float a, float b) {
    __hip_bfloat162 t = __float22bfloat162_rn(float2{a, b});   // v_cvt_pk_bf16_f32
    union { __hip_bfloat162 b; unsigned u; } v; v.b = t;
    return v.u;
}
// packed FP32 ops (VOP3P, CDNA2+)
__device__ __forceinline__ f32x2 pk_add2(f32x2 a, f32x2 b) {
    f32x2 d;
    asm("v_pk_add_f32 %0, %1, %2" : "=v"(d) : "v"(a), "v"(b));
    return d;
}
__device__ __forceinline__ f32x2 pk_mul2(f32x2 a, f32x2 b) {
    f32x2 d;
    asm("v_pk_mul_f32 %0, %1, %2" : "=v"(d) : "v"(a), "v"(b));
    return d;
}

// ---------------------------------------------------------------------------
// R11 = R6 VERBATIM (best verified: rocprof ~326us, harness 366.6us).
// Session ceiling evidence (R6-R10): MfmaUtil+VALUBusy caps at ~95% with
// every explicit overlap structure (sleep-stagger, intra-wave 2-acc dbuf,
// cross-wave role split x2 mappings) REDUCING it -> per-SIMD issue-port
// contention between MFMA operand/issue occupancy and wave64 VALU 2-cyc
// issue is the structural limit for alternating-role waves. Time ~=
// VALU-busy (170us, exp2-floor) + MFMA-busy (140us, bf16 rate) + barrier
// drain. R6's natural 4-block/SIMD TLP is the max-overlap configuration.
//
// Wave tile = 64 rows x 64 cols. Wave w owns phys cols [w*64, w*64+64).
// Pack order per layer: frag-set ((w*NKS+ks)*4+ct) -> contiguous stream.
//   wp[(((w*NKS+ks)*4+ct)*64 + lane)*8 + j] = s_n * W[k][n],
//   k = ks*32 + (lane>>4)*8 + j,  n = w*64 + 4*(lane&15) + ct.
// SCALE FOLD: s_n = sqrt(log2e/(2 sigma_n^2)) folded into W; t_n = s_n*b_n.
// Gaussian = exp2(-(u + t)^2): pk_add + pk_mul + exp2(neg mod, free).
// W0: hi/lo split rows [wh,wl,wh] per input dim (K=9 pad 32, NKS=1).
// W3: hi/lo split into 2 B-columns at wp+139264 (unscaled).
// negc[l*256 + n] = t_n.
// Register budget: acc 64 AGPR + <=64 VGPR <= 128 total (crossing 128 =
// occupancy cliff R2 / scratch spill R8). __launch_bounds__(256,4) pins it.
// ---------------------------------------------------------------------------
__global__ void pack_kernel(const float* __restrict__ W0, const float* __restrict__ W1,
                            const float* __restrict__ W2, const float* __restrict__ W3,
                            const float* __restrict__ s0, const float* __restrict__ s1,
                            const float* __restrict__ s2,
                            const float* __restrict__ b0, const float* __restrict__ b1,
                            const float* __restrict__ b2,
                            unsigned short* __restrict__ wp, float* __restrict__ negc) {
    int tid = blockIdx.x * 256 + threadIdx.x;    // 0 .. 143359
    if (tid < 8192) {                            // W0 (NKS=1), scaled hi/lo
        int j = tid & 7, lane = (tid >> 3) & 63, ct = (tid >> 9) & 3, w = tid >> 11;
        int k = ((lane >> 4) * 8) + j;           // 0..31
        int n = w * 64 + 4 * (lane & 15) + ct;
        unsigned short v = 0;
        if (k < 9) {
            int d = k / 3, m = k - d * 3;        // m: 0->wh 1->wl 2->wh
            float sv = s0[n];
            float sc = sqrtf(LOG2E / (2.0f * sv * sv));
            float wv = W0[d * 256 + n] * sc;
            unsigned short wh = f2bf(wv);
            v = (m == 1) ? f2bf(wv - bf2f(wh)) : wh;
        }
        wp[tid] = v;
    } else if (tid < 139264) {                   // W1 / W2 (NKS=8), scaled
        int e = tid - 8192;
        const float* W = W1;
        const float* S = s1;
        if (e >= 65536) { W = W2; S = s2; e -= 65536; }
        int j = e & 7, lane = (e >> 3) & 63, ct = (e >> 9) & 3, ks = (e >> 11) & 7, w = e >> 14;
        int k = ks * 32 + ((lane >> 4) * 8) + j;
        int n = w * 64 + 4 * (lane & 15) + ct;
        float sv = S[n];
        float sc = sqrtf(LOG2E / (2.0f * sv * sv));
        wp[tid] = f2bf(W[k * 256 + n] * sc);     // full-offset store
    } else if (tid < 143360) {                   // W3 hi/lo (2 B-cols), unscaled
        int e = tid - 139264;
        int j = e & 7, lane = (e >> 3) & 63, ks = (e >> 9) & 1, w = e >> 10;
        int i16p = lane & 15, qp = lane >> 4;
        int k = w * 64 + ks * 32 + qp * 8 + j;
        float wv = W3[k];
        unsigned short wh = f2bf(wv);
        unsigned short v = 0;
        if (i16p == 0) v = wh;
        else if (i16p == 1) v = f2bf(wv - bf2f(wh));
        wp[139264 + e] = v;
    }
    if (tid < 768) {
        int l = tid >> 8, n = tid & 255;
        const float* s = (l == 0) ? s0 : (l == 1 ? s1 : s2);
        const float* b = (l == 0) ? b0 : (l == 1 ? b1 : b2);
        float sv = s[n], bv = b[n];
        float sc = sqrtf(LOG2E / (2.0f * sv * sv));
        negc[l * 256 + n] = sc * bv;             // t_n
    }
}

constexpr int ROWS = 64;     // rows per block (256 threads = 4 waves)
constexpr int HSTR = 264;    // h row stride, bf16 elems (+8 pad; 528 B)
constexpr int ASTR = 40;     // A0 row stride (80 B)

// One MFMA layer. Each wave: all 64 rows x its 64 cols. Per ks: 4 A-frags
// (rg) + 4 W-frags (ct, contiguous stream) -> 16 MFMAs (each load feeds 4).
// acc[rg][ct]; activations packed to regs BEFORE the presync barrier.
// Activation: pk_add + pk_mul + exp2(-w) per element pair.
template <int NKS, int SSTR>
__device__ __forceinline__ void layer(const unsigned short* __restrict__ src,
                                      const unsigned short* __restrict__ wpk,
                                      const float* __restrict__ ncp,
                                      unsigned short* __restrict__ hdst,
                                      int w, int i16, int q, bool presync) {
    f32x4 acc[4][4];
#pragma unroll
    for (int rg = 0; rg < 4; ++rg)
#pragma unroll
        for (int ct = 0; ct < 4; ++ct)
            acc[rg][ct] = f32x4{0.f, 0.f, 0.f, 0.f};

    const int lane = q * 16 + i16;
    const short8* wp8 = (const short8*)wpk + (w * NKS * 4) * 64 + lane;
    const unsigned short* abase = src + i16 * SSTR + q * 8;

    __builtin_amdgcn_s_setprio(1);   // T5: favor MFMA-phase wave on the SIMD
#pragma unroll
    for (int ks = 0; ks < NKS; ++ks) {
        short8 a[4];
#pragma unroll
        for (int rg = 0; rg < 4; ++rg)
            a[rg] = *(const short8*)(abase + rg * 16 * SSTR + ks * 32);
#pragma unroll
        for (int ct = 0; ct < 4; ++ct) {
            short8 wf = wp8[(ks * 4 + ct) * 64];
#pragma unroll
            for (int rg = 0; rg < 4; ++rg)
                acc[rg][ct] = __builtin_amdgcn_mfma_f32_16x16x32_bf16(a[rg], wf, acc[rg][ct], 0, 0, 0);
        }
    }
    __builtin_amdgcn_s_setprio(0);   // activation phase yields priority

    // ---- activation math BEFORE barrier ----
    const int ce = w * 64 + 4 * i16;
    const f32x4 T = *(const f32x4*)(ncp + ce);
    f32x2 tb[4];
#pragma unroll
    for (int ct = 0; ct < 4; ++ct) tb[ct] = f32x2{T[ct], T[ct]};
    uint2v av[4][4];
#pragma unroll
    for (int rg = 0; rg < 4; ++rg) {
        float gg[4][4];   // [rr][ct]
#pragma unroll
        for (int ct = 0; ct < 4; ++ct) {
            f32x2 xlo = f32x2{acc[rg][ct][0], acc[rg][ct][1]};
            f32x2 xhi = f32x2{acc[rg][ct][2], acc[rg][ct][3]};
            f32x2 ylo = pk_add2(xlo, tb[ct]);
            f32x2 yhi = pk_add2(xhi, tb[ct]);
            f32x2 wlo = pk_mul2(ylo, ylo);
            f32x2 whi = pk_mul2(yhi, yhi);
            gg[0][ct] = __builtin_amdgcn_exp2f(-wlo[0]);
            gg[1][ct] = __builtin_amdgcn_exp2f(-wlo[1]);
            gg[2][ct] = __builtin_amdgcn_exp2f(-whi[0]);
            gg[3][ct] = __builtin_amdgcn_exp2f(-whi[1]);
        }
#pragma unroll
        for (int rr = 0; rr < 4; ++rr) {
            uint2v v;
            v[0] = pk_bf16(gg[rr][0], gg[rr][1]);
            v[1] = pk_bf16(gg[rr][2], gg[rr][3]);
            av[rg][rr] = v;
        }
    }
    if (presync) __syncthreads();   // all reads of hdst done before overwrite
#pragma unroll
    for (int rg = 0; rg < 4; ++rg) {
        int rbase = rg * 16 + q * 4;
#pragma unroll
        for (int rr = 0; rr < 4; ++rr)
            *(uint2v*)&hdst[(rbase + rr) * HSTR + ce] = av[rg][rr];
    }
    __syncthreads();
}

__global__ __launch_bounds__(256, 4) void mlp_kernel(
    const float* __restrict__ pos,
    const float* __restrict__ b3,
    const unsigned short* __restrict__ Wp,
    const float* __restrict__ negc,
    float* __restrict__ out)
{
    __shared__ unsigned short h[ROWS * HSTR];   // 33792 B
    __shared__ unsigned short A0[ROWS * ASTR];  // 5120 B (reused as f32 scratch)

    const int tid  = threadIdx.x;
    const int lane = tid & 63;
    const int wave = tid >> 6;                  // column group (0..3)
    const int i16  = lane & 15, q = lane >> 4;
    const long row0 = (long)blockIdx.x * ROWS;

    // ---- build A0: row r = [p0h,p0h,p0l, p1h,p1h,p1l, p2h,p2h,p2l, 0...] ----
    if (tid < ROWS) {
        const float* pp = pos + (row0 + tid) * 3;
        float p0 = pp[0], p1 = pp[1], p2 = pp[2];
        short h0 = (short)f2bf(p0); short l0 = (short)f2bf(p0 - bf2f((unsigned short)h0));
        short h1 = (short)f2bf(p1); short l1 = (short)f2bf(p1 - bf2f((unsigned short)h1));
        short h2 = (short)f2bf(p2); short l2 = (short)f2bf(p2 - bf2f((unsigned short)h2));
        unsigned short* arow = A0 + tid * ASTR;
        *(short8*)(arow + 0)  = short8{h0, h0, l0, h1, h1, l1, h2, h2};
        *(short8*)(arow + 8)  = short8{l2, 0, 0, 0, 0, 0, 0, 0};
        *(short8*)(arow + 16) = short8{0, 0, 0, 0, 0, 0, 0, 0};
        *(short8*)(arow + 24) = short8{0, 0, 0, 0, 0, 0, 0, 0};
    }
    __syncthreads();

    // ---- layer 0 (MFMA K=32 hi/lo), layers 1,2 ----
    layer<1, ASTR>(A0, Wp,         negc,        h, wave, i16, q, false);
    layer<8, HSTR>(h,  Wp + 8192,  negc + 256,  h, wave, i16, q, true);
    layer<8, HSTR>(h,  Wp + 73728, negc + 512,  h, wave, i16, q, true);

    // ---- layer 3: per-wave K-slice dot via MFMA (hi/lo W3 in B-cols 0,1) ----
    {
        const short8* w3p = (const short8*)(Wp + 139264) + (wave * 2) * 64 + lane;
        const unsigned short* ab3 = h + i16 * HSTR + wave * 64 + q * 8;
        f32x4 acc3[4];
#pragma unroll
        for (int rg = 0; rg < 4; ++rg) acc3[rg] = f32x4{0.f, 0.f, 0.f, 0.f};
        __builtin_amdgcn_s_setprio(1);
#pragma unroll
        for (int ks = 0; ks < 2; ++ks) {
            short8 wf = w3p[ks * 64];
#pragma unroll
            for (int rg = 0; rg < 4; ++rg) {
                short8 a = *(const short8*)(ab3 + rg * 16 * HSTR + ks * 32);
                acc3[rg] = __builtin_amdgcn_mfma_f32_16x16x32_bf16(a, wf, acc3[rg], 0, 0, 0);
            }
        }
        __builtin_amdgcn_s_setprio(0);
        // acc3[rg][rr]: col = i16 (0: wh-part, 1: wl-part), row = rg*16+q*4+rr
        float* scr = (float*)A0;   // [wave*2+i16][64 rows] = 2 KB
        if (i16 < 2) {
#pragma unroll
            for (int rg = 0; rg < 4; ++rg)
                *(f32x4*)&scr[(wave * 2 + i16) * 64 + rg * 16 + q * 4] = acc3[rg];
        }
        __syncthreads();
        if (tid < 64) {
            float s = 0.f;
#pragma unroll
            for (int g = 0; g < 8; ++g) s += scr[g * 64 + tid];
            float x  = s + b3[0];
            float xm = fminf(x, 8.0f);
            float e  = __builtin_amdgcn_exp2f(xm * LOG2E);
            float sp = __builtin_amdgcn_logf(1.0f + e) * LN2;
            out[row0 + tid] = (x > 8.0f) ? x : sp;
        }
    }
}

extern "C" void kernel_launch(void* const* d_in, const int* in_sizes, int n_in,
                              void* d_out, int out_size, void* d_ws, size_t ws_size,
                              hipStream_t stream) {
    const float* pos = (const float*)d_in[0];
    const float* W0  = (const float*)d_in[1];
    const float* b0  = (const float*)d_in[2];
    const float* W1  = (const float*)d_in[3];
    const float* b1  = (const float*)d_in[4];
    const float* W2  = (const float*)d_in[5];
    const float* b2  = (const float*)d_in[6];
    const float* W3  = (const float*)d_in[7];
    const float* b3  = (const float*)d_in[8];
    const float* s0  = (const float*)d_in[9];
    const float* s1  = (const float*)d_in[10];
    const float* s2  = (const float*)d_in[11];

    unsigned short* wp = (unsigned short*)d_ws;              // 143360 bf16
    float* negc = (float*)((char*)d_ws + 286720);            // 768 fp32: 3 x t[256]

    pack_kernel<<<560, 256, 0, stream>>>(W0, W1, W2, W3, s0, s1, s2, b0, b1, b2, wp, negc);

    int nrows = in_sizes[0] / 3;          // 1048576
    int nblk  = nrows / ROWS;             // 16384
    mlp_kernel<<<nblk, 256, 0, stream>>>(pos, b3, wp, negc,
                                         (float*)d_out);
}